// Round 12
// baseline (581.841 us; speedup 1.0000x reference)
//
#include <hip/hip_runtime.h>
#include <hip/hip_bf16.h>
#include <hip/hip_fp16.h>

typedef unsigned short u16;
typedef unsigned int u32;

#define N_NODES 100000
#define N_EDGES 600000
#define FIN_D   256
#define HDIM    128
#define NCLS    47
#define NOUT_D  10000
#define NCHUNK  196          // ceil(N_NODES/512)
#define NP2     100352       // NCHUNK*512, padded node count
#define PCH     2048         // edges per partition block
#define PNB     ((N_EDGES + PCH - 1) / PCH)   // 293
#define EB      1024         // edges per histB block

typedef short bf16x8 __attribute__((ext_vector_type(8)));
typedef float f32x4  __attribute__((ext_vector_type(4)));

#define GPTR(p) (const __attribute__((address_space(1))) u32*)(p)
#define LPTR(p) (__attribute__((address_space(3))) u32*)(p)

__device__ __forceinline__ float bf2f(u16 u) {
    union { u32 i; float f; } v; v.i = ((u32)u) << 16; return v.f;
}
__device__ __forceinline__ u16 f2bf(float f) {
    __hip_bfloat16 h = __float2bfloat16(f);
    return *reinterpret_cast<u16*>(&h);
}
__device__ __forceinline__ float loadF(const void* p, size_t i, bool f32) {
    if (f32) return ((const float*)p)[i];
    return bf2f(((const u16*)p)[i]);
}
__device__ __forceinline__ float wave_sum(float v) {
    #pragma unroll
    for (int o = 32; o > 0; o >>= 1) v += __shfl_xor(v, o, 64);
    return v;
}
__device__ __forceinline__ float wave_max(float v) {
    #pragma unroll
    for (int o = 32; o > 0; o >>= 1) v = fmaxf(v, __shfl_xor(v, o, 64));
    return v;
}
__device__ __forceinline__ int block_excl_scan_256(int v, int* wsum) {
    int lane = threadIdx.x & 63, wv = threadIdx.x >> 6;
    int inc = v;
    #pragma unroll
    for (int off = 1; off < 64; off <<= 1) {
        int u = __shfl_up(inc, off, 64);
        if (lane >= off) inc += u;
    }
    if (lane == 63) wsum[wv] = inc;
    __syncthreads();
    if (threadIdx.x == 0) {
        int a = 0;
        #pragma unroll
        for (int w = 0; w < 4; ++w) { int t = wsum[w]; wsum[w] = a; a += t; }
    }
    __syncthreads();
    return inc - v + wsum[wv];
}

// ---------------- dtype detector (parallel, 256 blocks) -----------------
__global__ __launch_bounds__(256) void dtype_detect_kernel(
    const u16* __restrict__ x, int* __restrict__ flag)
{
    int i = blockIdx.x * 256 + threadIdx.x;     // exactly 65536 threads
    u32 e = (x[i] >> 7) & 0xFF;
    unsigned long long b = __ballot(e >= 200);
    if ((threadIdx.x & 63) == 0) {
        int c = __popcll(b);
        if (c) atomicAdd(&flag[1], c);
    }
}

// ---------------- CSR build v11 -----------------------------------------
// histB: 196-bin bucket histogram via LDS (cheap; feeds coff2 directly).
__global__ __launch_bounds__(256) void histb_kernel(
    const int* __restrict__ dst, int* __restrict__ bcnt, int ebgrid)
{
    __shared__ int h[NCHUNK];
    int half = (blockIdx.x >= ebgrid) ? 1 : 0;
    int e0 = (blockIdx.x - half * ebgrid) * EB;
    for (int i = threadIdx.x; i < NCHUNK; i += 256) h[i] = 0;
    __syncthreads();
    #pragma unroll
    for (int t = 0; t < 4; ++t) {
        int e = e0 + t * 256 + threadIdx.x;
        if (e < N_EDGES) atomicAdd(&h[dst[half * N_EDGES + e] >> 9], 1);
    }
    __syncthreads();
    for (int i = threadIdx.x; i < NCHUNK; i += 256)
        if (h[i]) atomicAdd(&bcnt[half * NCHUNK + i], h[i]);
}

// exclusive-scan per-bucket counts; coff compact, bcur padded 1/cacheline.
__global__ __launch_bounds__(256) void coff2_kernel(
    const int* __restrict__ csum, int* __restrict__ coff,
    int* __restrict__ bcur)
{
    __shared__ int wsum[4];
    int t = threadIdx.x;
    for (int h = 0; h < 2; ++h) {
        int v = (t < NCHUNK) ? csum[h * NCHUNK + t] : 0;
        int excl = block_excl_scan_256(v, wsum);
        if (t < NCHUNK) {
            coff[h * NCHUNK + t] = excl;
            bcur[(h * NCHUNK + t) * 16] = excl;   // 64B-padded cursor
        }
        __syncthreads();
    }
}

// Pass 1: block-local radix partition. tmp packed u32: (src<<9)|(dst&511)
// (src < 2^17, bucket-local dst is 9 bits) -- halves tmp traffic.
__global__ __launch_bounds__(256) void bucket_part_kernel(
    const int* __restrict__ src, const int* __restrict__ dst,
    const int* __restrict__ comp1,
    int* __restrict__ bcur, u32* __restrict__ tmp)
{
    __shared__ int hist[NCHUNK];
    __shared__ int base[NCHUNK];
    int half = (blockIdx.x >= PNB) ? 1 : 0;
    int b = blockIdx.x - half * PNB;
    int e0 = b * PCH;
    for (int i = threadIdx.x; i < NCHUNK; i += 256) hist[i] = 0;
    __syncthreads();

    int2 loc[8];
    #pragma unroll
    for (int t = 0; t < 8; ++t) {
        int e = e0 + t * 256 + threadIdx.x;
        loc[t].y = -1;
        if (e < N_EDGES) {
            int ge = half * N_EDGES + e;
            int d = dst[ge];
            int s = src[ge];
            if (half) s = comp1[s];
            loc[t] = make_int2(s, d);
            atomicAdd(&hist[d >> 9], 1);
        }
    }
    __syncthreads();
    for (int i = threadIdx.x; i < NCHUNK; i += 256) {
        int h = hist[i];
        base[i] = (h > 0) ? atomicAdd(&bcur[(half * NCHUNK + i) * 16], h) : 0;
        hist[i] = 0;      // reuse as block-local cursor
    }
    __syncthreads();
    #pragma unroll
    for (int t = 0; t < 8; ++t) {
        if (loc[t].y >= 0) {
            int bk = loc[t].y >> 9;
            int pos = base[bk] + atomicAdd(&hist[bk], 1);
            tmp[(size_t)half * N_EDGES + pos] =
                ((u32)loc[t].x << 9) | ((u32)loc[t].y & 511);
        }
    }
}

// Pass 2 (v10): one block per bucket; local degree histogram -> rp
// (coalesced; replaces scan2 + random degree atomics), then rank+scatter.
__global__ __launch_bounds__(256) void bucket_sort_kernel(
    const u32* __restrict__ tmp,
    const int* __restrict__ coff, const int* __restrict__ csum,
    int* __restrict__ rp0, int* __restrict__ rp1,
    int* __restrict__ ei0, int* __restrict__ ei1)
{
    __shared__ int cur[512];
    __shared__ int wsum[4];
    int half = (blockIdx.x >= NCHUNK) ? 1 : 0;
    int b = blockIdx.x - half * NCHUNK;
    int* rp = half ? rp1 : rp0;
    int* ei = half ? ei1 : ei0;
    int n0 = b * 512;
    int beg = coff[half * NCHUNK + b];
    int end = beg + csum[half * NCHUNK + b];
    const int t = threadIdx.x;

    // pass 1: local degree histogram (LDS atomics)
    cur[t] = 0; cur[t + 256] = 0;
    __syncthreads();
    for (int i = beg + t; i < end; i += 256)
        atomicAdd(&cur[tmp[(size_t)half * N_EDGES + i] & 511], 1);
    __syncthreads();

    // 512-entry exclusive scan (2 per thread); own-entry read/write only
    int d0 = cur[2 * t], d1 = cur[2 * t + 1];
    int excl = block_excl_scan_256(d0 + d1, wsum);
    int base = beg + excl;
    cur[2 * t] = base;
    cur[2 * t + 1] = base + d0;
    if (n0 + 2 * t <= N_NODES)     rp[n0 + 2 * t] = base;
    if (n0 + 2 * t + 1 <= N_NODES) rp[n0 + 2 * t + 1] = base + d0;
    __syncthreads();

    // pass 2: rank + scatter
    for (int i = beg + t; i < end; i += 256) {
        u32 p = tmp[(size_t)half * N_EDGES + i];
        int pos = atomicAdd(&cur[p & 511], 1);
        ei[pos] = (int)(p >> 9);
    }
}

// ---------------- Weight pre-pack into MFMA B-fragment order -----------
__global__ __launch_bounds__(256) void pack_b_kernel(
    const void* __restrict__ enc_w, const void* __restrict__ gcn_w,
    const int* __restrict__ dt, u16* __restrict__ Bp)
{
    const bool f32 = (dt[1] > 16);
    int o = blockIdx.x * 256 + threadIdx.x;
    if (o >= 32768 + 3 * 16384) return;
    const void* srcp; size_t soff; int m;
    if (o < 32768) { srcp = enc_w; soff = 0; m = o; }
    else {
        int l = (o - 32768) >> 14;
        srcp = gcn_w; soff = (size_t)l * 16384; m = (o - 32768) & 16383;
    }
    int j    = m & 7;
    int lane = (m >> 3) & 63;
    int ct   = (m >> 9) & 7;
    int kidx = m >> 12;
    int k = kidx * 32 + (lane >> 4) * 8 + j;
    int n = ct * 16 + (lane & 15);
    Bp[o] = f2bf(loadF(srcp, soff + (size_t)k * HDIM + n, f32));
}

// ---------------- Encoder GEMM (v6 structure, banked ~62us) -------------
__global__ __launch_bounds__(256, 2) void enc_gemm_kernel(
    const void* __restrict__ Araw, const u16* __restrict__ Bp,
    const void* __restrict__ bias, const int* __restrict__ dt,
    u16* __restrict__ OutBF)
{
    extern __shared__ char SH[];                  // 80KB: [0,64K)=B, [64K,80K)=A
    const bool f32 = (dt[1] > 16);
    const int tid  = threadIdx.x;
    const int w    = tid >> 6;                    // 0..3
    const int lane = tid & 63;
    const int quad = lane >> 4;
    const int cl   = lane & 15;
    const int m0   = blockIdx.x * 16;

    #pragma unroll
    for (int i = 0; i < 16; ++i) {
        int off = (w * 16 + i) * 1024;
        __builtin_amdgcn_global_load_lds(
            GPTR((const char*)Bp + off + lane * 16),
            LPTR(SH + off), 16, 0, 0);
    }
    if (f32) {
        #pragma unroll
        for (int i = 0; i < 4; ++i) {
            int row = w * 4 + i;
            int src = (lane * 16) ^ ((row & 7) << 4);
            __builtin_amdgcn_global_load_lds(
                GPTR((const char*)Araw + (size_t)(m0 + row) * 1024 + src),
                LPTR(SH + 65536 + row * 1024), 16, 0, 0);
        }
    } else {
        #pragma unroll
        for (int i = 0; i < 2; ++i) {
            int r0 = (w * 2 + i) * 2;
            int row = r0 + (lane >> 5);
            int src = ((lane & 31) * 16) ^ ((row & 7) << 4);
            __builtin_amdgcn_global_load_lds(
                GPTR((const char*)Araw + (size_t)(m0 + row) * 512 + src),
                LPTR(SH + 65536 + r0 * 512), 16, 0, 0);
        }
    }

    f32x4 acc[2];
    acc[0] = (f32x4){0.f, 0.f, 0.f, 0.f};
    acc[1] = (f32x4){0.f, 0.f, 0.f, 0.f};
    const int ct0 = w * 2;
    const int swz = (cl & 7) << 4;

    __syncthreads();

    #pragma unroll
    for (int k = 0; k < 8; ++k) {
        bf16x8 av;
        if (f32) {
            const char* rb = SH + 65536 + cl * 1024;
            int lo = (k * 128 + quad * 32) ^ swz;
            float4 v0 = *(const float4*)(rb + lo);
            float4 v1 = *(const float4*)(rb + (lo ^ 16));
            union { u32 u[4]; bf16x8 v; } cv;
            cv.u[0] = (u32)f2bf(v0.x) | ((u32)f2bf(v0.y) << 16);
            cv.u[1] = (u32)f2bf(v0.z) | ((u32)f2bf(v0.w) << 16);
            cv.u[2] = (u32)f2bf(v1.x) | ((u32)f2bf(v1.y) << 16);
            cv.u[3] = (u32)f2bf(v1.z) | ((u32)f2bf(v1.w) << 16);
            av = cv.v;
        } else {
            const char* rb = SH + 65536 + cl * 512;
            av = *(const bf16x8*)(rb + ((k * 64 + quad * 16) ^ swz));
        }
        #pragma unroll
        for (int c = 0; c < 2; ++c) {
            bf16x8 b = *(const bf16x8*)(SH + k * 8192 + (ct0 + c) * 1024 + lane * 16);
            acc[c] = __builtin_amdgcn_mfma_f32_16x16x32_bf16(av, b, acc[c], 0, 0, 0);
        }
    }

    #pragma unroll
    for (int reg = 0; reg < 4; ++reg) {
        int grow = m0 + quad * 4 + reg;
        #pragma unroll
        for (int c = 0; c < 2; ++c) {
            int col = (ct0 + c) * 16 + cl;
            float v = acc[c][reg] + loadF(bias, col, f32);
            OutBF[(size_t)grow * HDIM + col] = f2bf(v);
        }
    }
}

// ---------------- Softmax aggregation -> bf16 A-matrix (v7) -------------
template<bool OWN_MAP>
__global__ __launch_bounds__(256) void agg_msg_kernel(
    const int* __restrict__ rp, const int* __restrict__ eidx,
    const u16* __restrict__ HBin, const int* __restrict__ own_map,
    u16* __restrict__ Amsg)
{
    __shared__ u32 RS[4][16][64];   // 16KB: per-wave staging of 16 rows
    int wave = threadIdx.x >> 6;
    int lane = threadIdx.x & 63;
    int n = blockIdx.x * 4 + wave;
    if (n >= N_NODES) return;       // no barriers below: wave-local only
    const u32* HB32 = (const u32*)HBin;
    int nn = OWN_MAP ? own_map[n] : n;
    u32 own = HB32[(size_t)nn * 64 + lane];
    int beg = rp[n], end = rp[n + 1];
    float den0 = 0.f, den1 = 0.f, num0 = 0.f, num1 = 0.f;
    for (int c = beg; c < end; c += 16) {
        int cnt = end - c; if (cnt > 16) cnt = 16;
        int e = c + (lane & 15); if (e > end - 1) e = end - 1;
        int ei = eidx[e];                       // lanes 0..15 hold the ids
        int nI = (cnt + 3) >> 2;
        #pragma unroll
        for (int i = 0; i < 4; ++i) {
            if (i < nI) {
                int s = __shfl(ei, i * 4 + (lane >> 4), 64);
                __builtin_amdgcn_global_load_lds(
                    GPTR((const char*)HBin + (size_t)s * 256 + (lane & 15) * 16),
                    LPTR(&RS[wave][i * 4][0]), 16, 0, 0);
            }
        }
        asm volatile("s_waitcnt vmcnt(0)" ::: "memory");
        __builtin_amdgcn_sched_barrier(0);
        #pragma unroll
        for (int t = 0; t < 16; ++t) {
            if (t >= cnt) break;                // cnt is wave-uniform
            u32 h = RS[wave][t][lane];
            float m0 = fmaxf(bf2f((u16)(h & 0xffff)), 0.f) + 1e-7f;
            float m1 = fmaxf(bf2f((u16)(h >> 16)),    0.f) + 1e-7f;
            float e0 = __expf(m0), e1 = __expf(m1);
            den0 += e0; num0 += m0 * e0;
            den1 += e1; num1 += m1 * e1;
        }
        asm volatile("s_waitcnt lgkmcnt(0)" ::: "memory");  // reads done before
        __builtin_amdgcn_sched_barrier(0);                  // next DMA overwrite
    }
    float a0 = num0 / (den0 + 1e-16f) + bf2f((u16)(own & 0xffff));
    float a1 = num1 / (den1 + 1e-16f) + bf2f((u16)(own >> 16));
    ((u32*)Amsg)[(size_t)n * 64 + lane] = (u32)f2bf(a0) | ((u32)f2bf(a1) << 16);
}

// ---------------- Conv GEMM v8: 128 rows/block (halved B-restage) -------
template<bool RES, bool OWN_MAP, bool WRITE_LN>
__global__ __launch_bounds__(256, 2) void conv_gemm_kernel(
    const u16* __restrict__ Amsg, const int* __restrict__ own_map,
    const u16* __restrict__ Bp, int Bpbase,
    const void* __restrict__ bias, int biasoff,
    const __half* __restrict__ Resid,
    const void* __restrict__ lng, const void* __restrict__ lnb, int lnoff,
    const int* __restrict__ dt,
    __half* __restrict__ OutH, u16* __restrict__ HBout)
{
    const bool f32 = (dt[1] > 16);
    __shared__ u16 Bsh[16384];      // 32KB
    __shared__ u16 Ash[16384];      // 32KB: 128 rows x 256B (swizzled)
    const int tid  = threadIdx.x;
    const int w    = tid >> 6;
    const int lane = tid & 63;
    const int quad = lane >> 4;
    const int cl   = lane & 15;
    const int m0   = blockIdx.x * 128;

    {
        const char* Bp2 = (const char*)(Bp + Bpbase);
        #pragma unroll
        for (int i = 0; i < 8; ++i)
            __builtin_amdgcn_global_load_lds(
                GPTR(Bp2 + i * 4096 + w * 1024 + lane * 16),
                LPTR((char*)Bsh + i * 4096 + w * 1024), 16, 0, 0);
        const char* Ab = (const char*)Amsg + (size_t)m0 * 256;
        #pragma unroll
        for (int i = 0; i < 8; ++i) {
            int row_local = i * 16 + w * 4 + (lane >> 4);
            int off = ((lane & 15) * 16) ^ ((row_local & 7) << 4);
            __builtin_amdgcn_global_load_lds(
                GPTR(Ab + (size_t)row_local * 256 + off),
                LPTR((char*)Ash + i * 4096 + w * 1024), 16, 0, 0);
        }
    }

    __syncthreads();    // vmcnt(0) drain + barrier (compiler-emitted)

    bf16x8 afr[2][4];
    #pragma unroll
    for (int t = 0; t < 2; ++t) {
        const int row_local = w * 32 + t * 16 + cl;
        const char* ar = (const char*)Ash + row_local * 256;
        const int akey = (row_local & 7) << 4;
        #pragma unroll
        for (int kidx = 0; kidx < 4; ++kidx)
            afr[t][kidx] = *(const bf16x8*)(ar + ((kidx * 64 + quad * 16) ^ akey));
    }

    f32x4 acc[2][8];
    #pragma unroll
    for (int t = 0; t < 2; ++t)
        #pragma unroll
        for (int ct = 0; ct < 8; ++ct) acc[t][ct] = (f32x4){0.f, 0.f, 0.f, 0.f};
    #pragma unroll
    for (int kidx = 0; kidx < 4; ++kidx) {
        const u16* bb = Bsh + ((size_t)(kidx * 8) * 64 + lane) * 8;
        #pragma unroll
        for (int ct = 0; ct < 8; ++ct) {
            bf16x8 b = *(const bf16x8*)(bb + (size_t)ct * 512);
            acc[0][ct] = __builtin_amdgcn_mfma_f32_16x16x32_bf16(afr[0][kidx], b, acc[0][ct], 0, 0, 0);
            acc[1][ct] = __builtin_amdgcn_mfma_f32_16x16x32_bf16(afr[1][kidx], b, acc[1][ct], 0, 0, 0);
        }
    }

    #pragma unroll
    for (int t = 0; t < 2; ++t) {
        #pragma unroll
        for (int reg = 0; reg < 4; ++reg) {
            int n = m0 + w * 32 + t * 16 + quad * 4 + reg;
            if (n >= N_NODES) continue;
            size_t rrow = 0;
            if (RES) rrow = (size_t)(OWN_MAP ? own_map[n] : n) * HDIM;
            float v[8];
            float s1 = 0.f, s2 = 0.f;
            #pragma unroll
            for (int ct = 0; ct < 8; ++ct) {
                int col = ct * 16 + cl;
                float x = acc[t][ct][reg] + loadF(bias, biasoff + col, f32);
                if (RES) x += __half2float(Resid[rrow + col]);
                v[ct] = x;
                OutH[(size_t)n * HDIM + col] = __float2half(x);
                s1 += x; s2 += x * x;
            }
            if (WRITE_LN) {
                #pragma unroll
                for (int o = 1; o < 16; o <<= 1) {
                    s1 += __shfl_xor(s1, o, 64);
                    s2 += __shfl_xor(s2, o, 64);
                }
                float mu = s1 * (1.0f / 128.0f);
                float var = s2 * (1.0f / 128.0f) - mu * mu;
                float rs = rsqrtf(fmaxf(var, 0.f) + 1e-5f);
                #pragma unroll
                for (int ct = 0; ct < 8; ++ct) {
                    int col = ct * 16 + cl;
                    float y = fmaxf((v[ct] - mu) * rs * loadF(lng, lnoff + col, f32)
                                    + loadF(lnb, lnoff + col, f32), 0.f);
                    HBout[(size_t)n * HDIM + col] = f2bf(y);
                }
            }
        }
    }
}

// ---------------- Final head v3: 16 seeds/block (pred_w restage /4) -----
__global__ __launch_bounds__(256) void final_head_kernel(
    const __half* __restrict__ Hsrc, const int* __restrict__ map1,
    const int* __restrict__ fmap,
    const void* __restrict__ g, const void* __restrict__ b, int goff,
    const void* __restrict__ pw, const void* __restrict__ pb,
    const int* __restrict__ dt, void* __restrict__ out)
{
    const bool f32 = (dt[1] > 16);
    __shared__ float pwl[HDIM * 48];    // 24KB, stride-48-padded [k][cls]
    __shared__ float pbl[64];
    __shared__ float sh[4][4][HDIM];    // 8KB: [wave][seed][feat]
    const int tid = threadIdx.x, wave = tid >> 6, lane = tid & 63;

    for (int i = tid; i < HDIM * NCLS; i += 256)
        pwl[(i / NCLS) * 48 + (i % NCLS)] = loadF(pw, i, f32);
    if (tid < NCLS) pbl[tid] = loadF(pb, tid, f32);
    __syncthreads();

    #pragma unroll
    for (int js = 0; js < 4; ++js) {
        int i = blockIdx.x * 16 + wave * 4 + js;    // NOUT_D = 625*16
        int jj = map1[fmap[i]];
        __half2 hv = *((const __half2*)(Hsrc + (size_t)jj * HDIM) + lane);
        float2 v = __half22float2(hv);
        float mu = wave_sum(v.x + v.y) * (1.0f / 128.0f);
        float d0 = v.x - mu, d1 = v.y - mu;
        float var = wave_sum(d0 * d0 + d1 * d1) * (1.0f / 128.0f);
        float rs = rsqrtf(var + 1e-5f);
        int f0 = lane * 2;
        sh[wave][js][f0]     = fmaxf(d0 * rs * loadF(g, goff + f0, f32)     + loadF(b, goff + f0, f32),     0.0f);
        sh[wave][js][f0 + 1] = fmaxf(d1 * rs * loadF(g, goff + f0 + 1, f32) + loadF(b, goff + f0 + 1, f32), 0.0f);
        // wave-local LDS write->read; compiler inserts lgkmcnt, no barrier
        float acc = -1e30f;
        if (lane < NCLS) {
            acc = pbl[lane];
            #pragma unroll 8
            for (int k = 0; k < HDIM; ++k)
                acc = fmaf(sh[wave][js][k], pwl[k * 48 + lane], acc);
        }
        float mx = wave_max(acc);
        float ex = (lane < NCLS) ? __expf(acc - mx) : 0.0f;
        float sum = wave_sum(ex);
        if (lane < NCLS) {
            float r = acc - mx - logf(sum);
            if (f32) ((float*)out)[(size_t)i * NCLS + lane] = r;
            else     ((u16*)out)[(size_t)i * NCLS + lane] = f2bf(r);
        }
    }
}

extern "C" void kernel_launch(void* const* d_in, const int* in_sizes, int n_in,
                              void* d_out, int out_size, void* d_ws, size_t ws_size,
                              hipStream_t stream) {
    const void* x       = d_in[0];
    const int* src      = (const int*)d_in[1];
    const int* dst      = (const int*)d_in[2];
    const int* node_map = (const int*)d_in[3];
    const int* fmap     = (const int*)d_in[4];
    const void* enc_w   = d_in[5];
    const void* enc_b   = d_in[6];
    const void* gcn_w   = d_in[7];
    const void* gcn_b   = d_in[8];
    const void* ln_g    = d_in[9];
    const void* ln_b    = d_in[10];
    const void* pred_w  = d_in[11];
    const void* pred_b  = d_in[12];

    char* ws = (char*)d_ws;
    const size_t szH = (size_t)N_NODES * HDIM * sizeof(u16);     // 25.6 MB
    __half* Pa  = (__half*)ws;  ws += szH;   // h1, then h3 (fp16)
    __half* Pb  = (__half*)ws;  ws += szH;   // h2 (fp16)
    u16*   HBa  = (u16*)ws;     ws += szH;   // msg0, then msg2 (bf16)
    u16*   HBb  = (u16*)ws;     ws += szH;   // msg1 (bf16)
    u16*   Amsg = (u16*)ws;     ws += szH;   // per-layer GEMM A matrix (bf16)
    int*   FLAG = (int*)ws;     ws += 1024;
    u16*   Bp   = (u16*)ws;     ws += (size_t)(32768 + 3 * 16384) * 2 + 1024;
    int*  rp0   = (int*)ws;  ws += (size_t)(N_NODES + 2) * 4;
    int*  rp1   = (int*)ws;  ws += (size_t)(N_NODES + 2) * 4;
    int*  ei0   = (int*)ws;  ws += (size_t)N_EDGES * 4;
    int*  ei1   = (int*)ws;  ws += (size_t)N_EDGES * 4;
    u32*  tmp   = (u32*)ws;  ws += (size_t)2 * N_EDGES * 4;      // packed
    int*  csum  = (int*)ws;  ws += 2048;
    int*  coff  = (int*)ws;  ws += 2048;
    int*  bcur  = (int*)ws;  ws += (size_t)2 * NCHUNK * 16 * 4 + 1024;  // padded

    dim3 blk(256);
    const int g128  = (N_NODES + 127) / 128;     // 782 (conv, 128 rows/blk)
    const int g16   = (N_NODES + 15) / 16;       // 6250 (enc, 16 rows/blk)
    const int ebgrid = (N_EDGES + EB - 1) / EB;  // 586
    const int agrid = (N_NODES + 3) / 4;
    const int pgrid = (32768 + 3 * 16384 + 255) / 256;

    hipMemsetAsync(FLAG, 0, 64, stream);
    hipMemsetAsync(csum, 0, 2048, stream);
    dtype_detect_kernel<<<256, blk, 0, stream>>>((const u16*)x, FLAG);
    pack_b_kernel<<<pgrid, blk, 0, stream>>>(enc_w, gcn_w, FLAG, Bp);

    // ---- CSR build v11: bucket-hist -> coff -> partition -> sort(+rp) ----
    histb_kernel<<<2 * ebgrid, blk, 0, stream>>>(dst, csum, ebgrid);
    coff2_kernel<<<1, blk, 0, stream>>>(csum, coff, bcur);
    bucket_part_kernel<<<2 * PNB, blk, 0, stream>>>(src, dst, node_map, bcur, tmp);
    bucket_sort_kernel<<<2 * NCHUNK, blk, 0, stream>>>(tmp, coff, csum,
                                                       rp0, rp1, ei0, ei1);

    // encoder: HBa = bf16(x @ enc_w + enc_b)   (= msg matrix for conv0)
    enc_gemm_kernel<<<g16, blk, 81920, stream>>>(x, Bp, enc_b, FLAG, HBa);

    // layer 0: Amsg = agg0(HBa)+HBa ; Pa = Amsg@w0+b0 ; HBb = relu(LN(Pa,ln0))
    agg_msg_kernel<false><<<agrid, blk, 0, stream>>>(rp0, ei0, HBa, nullptr, Amsg);
    conv_gemm_kernel<false, false, true><<<g128, blk, 0, stream>>>(
        Amsg, nullptr, Bp, 32768, gcn_b, 0, nullptr,
        ln_g, ln_b, 0, FLAG, Pa, HBb);

    // layer 1: Amsg = agg0(HBb)+HBb ; Pb = Amsg@w1+b1+Pa ; HBa = relu(LN(Pb,ln1))
    agg_msg_kernel<false><<<agrid, blk, 0, stream>>>(rp0, ei0, HBb, nullptr, Amsg);
    conv_gemm_kernel<true, false, true><<<g128, blk, 0, stream>>>(
        Amsg, nullptr, Bp, 32768 + 16384, gcn_b, 128, Pa,
        ln_g, ln_b, 128, FLAG, Pb, HBa);

    // layer 2 (permute via node_map[0]): Amsg = agg1(HBa)+HBa[map0]
    agg_msg_kernel<true><<<agrid, blk, 0, stream>>>(rp1, ei1, HBa, node_map, Amsg);
    conv_gemm_kernel<true, true, false><<<g128, blk, 0, stream>>>(
        Amsg, node_map, Bp, 32768 + 2 * 16384, gcn_b, 256, Pb,
        ln_g, ln_b, 256, FLAG, Pa, nullptr);

    // final head: Pa[node_map[1][final_map[i]]] -> LN(ln2) -> pred -> log_softmax
    final_head_kernel<<<NOUT_D / 16, blk, 0, stream>>>(
        Pa, node_map + N_NODES, fmap, ln_g, ln_b, 256, pred_w, pred_b, FLAG,
        (void*)d_out);
}

// Round 13
// 542.721 us; speedup vs baseline: 1.0721x; 1.0721x over previous
//
#include <hip/hip_runtime.h>
#include <hip/hip_bf16.h>
#include <hip/hip_fp16.h>

typedef unsigned short u16;
typedef unsigned int u32;

#define N_NODES 100000
#define N_EDGES 600000
#define FIN_D   256
#define HDIM    128
#define NCLS    47
#define NOUT_D  10000
#define NCHUNK  196          // ceil(N_NODES/512)
#define NP2     100352       // NCHUNK*512, padded node count
#define PCH     2048         // edges per partition block
#define PNB     ((N_EDGES + PCH - 1) / PCH)   // 293
#define EB      1024         // edges per histB block

typedef short bf16x8 __attribute__((ext_vector_type(8)));
typedef float f32x4  __attribute__((ext_vector_type(4)));

#define GPTR(p) (const __attribute__((address_space(1))) u32*)(p)
#define LPTR(p) (__attribute__((address_space(3))) u32*)(p)

__device__ __forceinline__ float bf2f(u16 u) {
    union { u32 i; float f; } v; v.i = ((u32)u) << 16; return v.f;
}
__device__ __forceinline__ u16 f2bf(float f) {
    __hip_bfloat16 h = __float2bfloat16(f);
    return *reinterpret_cast<u16*>(&h);
}
__device__ __forceinline__ float loadF(const void* p, size_t i, bool f32) {
    if (f32) return ((const float*)p)[i];
    return bf2f(((const u16*)p)[i]);
}
__device__ __forceinline__ float wave_sum(float v) {
    #pragma unroll
    for (int o = 32; o > 0; o >>= 1) v += __shfl_xor(v, o, 64);
    return v;
}
__device__ __forceinline__ float wave_max(float v) {
    #pragma unroll
    for (int o = 32; o > 0; o >>= 1) v = fmaxf(v, __shfl_xor(v, o, 64));
    return v;
}
__device__ __forceinline__ int block_excl_scan_256(int v, int* wsum) {
    int lane = threadIdx.x & 63, wv = threadIdx.x >> 6;
    int inc = v;
    #pragma unroll
    for (int off = 1; off < 64; off <<= 1) {
        int u = __shfl_up(inc, off, 64);
        if (lane >= off) inc += u;
    }
    if (lane == 63) wsum[wv] = inc;
    __syncthreads();
    if (threadIdx.x == 0) {
        int a = 0;
        #pragma unroll
        for (int w = 0; w < 4; ++w) { int t = wsum[w]; wsum[w] = a; a += t; }
    }
    __syncthreads();
    return inc - v + wsum[wv];
}

// ---------------- dtype detector (parallel, 256 blocks) -----------------
__global__ __launch_bounds__(256) void dtype_detect_kernel(
    const u16* __restrict__ x, int* __restrict__ flag)
{
    int i = blockIdx.x * 256 + threadIdx.x;     // exactly 65536 threads
    u32 e = (x[i] >> 7) & 0xFF;
    unsigned long long b = __ballot(e >= 200);
    if ((threadIdx.x & 63) == 0) {
        int c = __popcll(b);
        if (c) atomicAdd(&flag[1], c);
    }
}

// ---------------- CSR build v11 -----------------------------------------
__global__ __launch_bounds__(256) void histb_kernel(
    const int* __restrict__ dst, int* __restrict__ bcnt, int ebgrid)
{
    __shared__ int h[NCHUNK];
    int half = (blockIdx.x >= ebgrid) ? 1 : 0;
    int e0 = (blockIdx.x - half * ebgrid) * EB;
    for (int i = threadIdx.x; i < NCHUNK; i += 256) h[i] = 0;
    __syncthreads();
    #pragma unroll
    for (int t = 0; t < 4; ++t) {
        int e = e0 + t * 256 + threadIdx.x;
        if (e < N_EDGES) atomicAdd(&h[dst[half * N_EDGES + e] >> 9], 1);
    }
    __syncthreads();
    for (int i = threadIdx.x; i < NCHUNK; i += 256)
        if (h[i]) atomicAdd(&bcnt[half * NCHUNK + i], h[i]);
}

// exclusive-scan per-bucket counts; coff compact, bcur padded 1/cacheline.
__global__ __launch_bounds__(256) void coff2_kernel(
    const int* __restrict__ csum, int* __restrict__ coff,
    int* __restrict__ bcur)
{
    __shared__ int wsum[4];
    int t = threadIdx.x;
    for (int h = 0; h < 2; ++h) {
        int v = (t < NCHUNK) ? csum[h * NCHUNK + t] : 0;
        int excl = block_excl_scan_256(v, wsum);
        if (t < NCHUNK) {
            coff[h * NCHUNK + t] = excl;
            bcur[(h * NCHUNK + t) * 16] = excl;   // 64B-padded cursor
        }
        __syncthreads();
    }
}

// Pass 1: block-local radix partition. tmp packed u32: (src<<9)|(dst&511).
__global__ __launch_bounds__(256) void bucket_part_kernel(
    const int* __restrict__ src, const int* __restrict__ dst,
    const int* __restrict__ comp1,
    int* __restrict__ bcur, u32* __restrict__ tmp)
{
    __shared__ int hist[NCHUNK];
    __shared__ int base[NCHUNK];
    int half = (blockIdx.x >= PNB) ? 1 : 0;
    int b = blockIdx.x - half * PNB;
    int e0 = b * PCH;
    for (int i = threadIdx.x; i < NCHUNK; i += 256) hist[i] = 0;
    __syncthreads();

    int2 loc[8];
    #pragma unroll
    for (int t = 0; t < 8; ++t) {
        int e = e0 + t * 256 + threadIdx.x;
        loc[t].y = -1;
        if (e < N_EDGES) {
            int ge = half * N_EDGES + e;
            int d = dst[ge];
            int s = src[ge];
            if (half) s = comp1[s];
            loc[t] = make_int2(s, d);
            atomicAdd(&hist[d >> 9], 1);
        }
    }
    __syncthreads();
    for (int i = threadIdx.x; i < NCHUNK; i += 256) {
        int h = hist[i];
        base[i] = (h > 0) ? atomicAdd(&bcur[(half * NCHUNK + i) * 16], h) : 0;
        hist[i] = 0;      // reuse as block-local cursor
    }
    __syncthreads();
    #pragma unroll
    for (int t = 0; t < 8; ++t) {
        if (loc[t].y >= 0) {
            int bk = loc[t].y >> 9;
            int pos = base[bk] + atomicAdd(&hist[bk], 1);
            tmp[(size_t)half * N_EDGES + pos] =
                ((u32)loc[t].x << 9) | ((u32)loc[t].y & 511);
        }
    }
}

// Pass 2: one block per bucket; local degree histogram -> rp, rank+scatter.
__global__ __launch_bounds__(256) void bucket_sort_kernel(
    const u32* __restrict__ tmp,
    const int* __restrict__ coff, const int* __restrict__ csum,
    int* __restrict__ rp0, int* __restrict__ rp1,
    int* __restrict__ ei0, int* __restrict__ ei1)
{
    __shared__ int cur[512];
    __shared__ int wsum[4];
    int half = (blockIdx.x >= NCHUNK) ? 1 : 0;
    int b = blockIdx.x - half * NCHUNK;
    int* rp = half ? rp1 : rp0;
    int* ei = half ? ei1 : ei0;
    int n0 = b * 512;
    int beg = coff[half * NCHUNK + b];
    int end = beg + csum[half * NCHUNK + b];
    const int t = threadIdx.x;

    // pass 1: local degree histogram (LDS atomics)
    cur[t] = 0; cur[t + 256] = 0;
    __syncthreads();
    for (int i = beg + t; i < end; i += 256)
        atomicAdd(&cur[tmp[(size_t)half * N_EDGES + i] & 511], 1);
    __syncthreads();

    // 512-entry exclusive scan (2 per thread); own-entry read/write only
    int d0 = cur[2 * t], d1 = cur[2 * t + 1];
    int excl = block_excl_scan_256(d0 + d1, wsum);
    int base = beg + excl;
    cur[2 * t] = base;
    cur[2 * t + 1] = base + d0;
    if (n0 + 2 * t <= N_NODES)     rp[n0 + 2 * t] = base;
    if (n0 + 2 * t + 1 <= N_NODES) rp[n0 + 2 * t + 1] = base + d0;
    __syncthreads();

    // pass 2: rank + scatter
    for (int i = beg + t; i < end; i += 256) {
        u32 p = tmp[(size_t)half * N_EDGES + i];
        int pos = atomicAdd(&cur[p & 511], 1);
        ei[pos] = (int)(p >> 9);
    }
}

// ---------------- Weight pre-pack into MFMA B-fragment order -----------
__global__ __launch_bounds__(256) void pack_b_kernel(
    const void* __restrict__ enc_w, const void* __restrict__ gcn_w,
    const int* __restrict__ dt, u16* __restrict__ Bp)
{
    const bool f32 = (dt[1] > 16);
    int o = blockIdx.x * 256 + threadIdx.x;
    if (o >= 32768 + 3 * 16384) return;
    const void* srcp; size_t soff; int m;
    if (o < 32768) { srcp = enc_w; soff = 0; m = o; }
    else {
        int l = (o - 32768) >> 14;
        srcp = gcn_w; soff = (size_t)l * 16384; m = (o - 32768) & 16383;
    }
    int j    = m & 7;
    int lane = (m >> 3) & 63;
    int ct   = (m >> 9) & 7;
    int kidx = m >> 12;
    int k = kidx * 32 + (lane >> 4) * 8 + j;
    int n = ct * 16 + (lane & 15);
    Bp[o] = f2bf(loadF(srcp, soff + (size_t)k * HDIM + n, f32));
}

// ---------------- Encoder GEMM (v6 structure, banked ~62us) -------------
__global__ __launch_bounds__(256, 2) void enc_gemm_kernel(
    const void* __restrict__ Araw, const u16* __restrict__ Bp,
    const void* __restrict__ bias, const int* __restrict__ dt,
    u16* __restrict__ OutBF)
{
    extern __shared__ char SH[];                  // 80KB: [0,64K)=B, [64K,80K)=A
    const bool f32 = (dt[1] > 16);
    const int tid  = threadIdx.x;
    const int w    = tid >> 6;                    // 0..3
    const int lane = tid & 63;
    const int quad = lane >> 4;
    const int cl   = lane & 15;
    const int m0   = blockIdx.x * 16;

    #pragma unroll
    for (int i = 0; i < 16; ++i) {
        int off = (w * 16 + i) * 1024;
        __builtin_amdgcn_global_load_lds(
            GPTR((const char*)Bp + off + lane * 16),
            LPTR(SH + off), 16, 0, 0);
    }
    if (f32) {
        #pragma unroll
        for (int i = 0; i < 4; ++i) {
            int row = w * 4 + i;
            int src = (lane * 16) ^ ((row & 7) << 4);
            __builtin_amdgcn_global_load_lds(
                GPTR((const char*)Araw + (size_t)(m0 + row) * 1024 + src),
                LPTR(SH + 65536 + row * 1024), 16, 0, 0);
        }
    } else {
        #pragma unroll
        for (int i = 0; i < 2; ++i) {
            int r0 = (w * 2 + i) * 2;
            int row = r0 + (lane >> 5);
            int src = ((lane & 31) * 16) ^ ((row & 7) << 4);
            __builtin_amdgcn_global_load_lds(
                GPTR((const char*)Araw + (size_t)(m0 + row) * 512 + src),
                LPTR(SH + 65536 + r0 * 512), 16, 0, 0);
        }
    }

    f32x4 acc[2];
    acc[0] = (f32x4){0.f, 0.f, 0.f, 0.f};
    acc[1] = (f32x4){0.f, 0.f, 0.f, 0.f};
    const int ct0 = w * 2;
    const int swz = (cl & 7) << 4;

    __syncthreads();

    #pragma unroll
    for (int k = 0; k < 8; ++k) {
        bf16x8 av;
        if (f32) {
            const char* rb = SH + 65536 + cl * 1024;
            int lo = (k * 128 + quad * 32) ^ swz;
            float4 v0 = *(const float4*)(rb + lo);
            float4 v1 = *(const float4*)(rb + (lo ^ 16));
            union { u32 u[4]; bf16x8 v; } cv;
            cv.u[0] = (u32)f2bf(v0.x) | ((u32)f2bf(v0.y) << 16);
            cv.u[1] = (u32)f2bf(v0.z) | ((u32)f2bf(v0.w) << 16);
            cv.u[2] = (u32)f2bf(v1.x) | ((u32)f2bf(v1.y) << 16);
            cv.u[3] = (u32)f2bf(v1.z) | ((u32)f2bf(v1.w) << 16);
            av = cv.v;
        } else {
            const char* rb = SH + 65536 + cl * 512;
            av = *(const bf16x8*)(rb + ((k * 64 + quad * 16) ^ swz));
        }
        #pragma unroll
        for (int c = 0; c < 2; ++c) {
            bf16x8 b = *(const bf16x8*)(SH + k * 8192 + (ct0 + c) * 1024 + lane * 16);
            acc[c] = __builtin_amdgcn_mfma_f32_16x16x32_bf16(av, b, acc[c], 0, 0, 0);
        }
    }

    #pragma unroll
    for (int reg = 0; reg < 4; ++reg) {
        int grow = m0 + quad * 4 + reg;
        #pragma unroll
        for (int c = 0; c < 2; ++c) {
            int col = (ct0 + c) * 16 + cl;
            float v = acc[c][reg] + loadF(bias, col, f32);
            OutBF[(size_t)grow * HDIM + col] = f2bf(v);
        }
    }
}

// ---------------- Softmax aggregation -> bf16 A-matrix (v7) -------------
template<bool OWN_MAP>
__global__ __launch_bounds__(256) void agg_msg_kernel(
    const int* __restrict__ rp, const int* __restrict__ eidx,
    const u16* __restrict__ HBin, const int* __restrict__ own_map,
    u16* __restrict__ Amsg)
{
    __shared__ u32 RS[4][16][64];   // 16KB: per-wave staging of 16 rows
    int wave = threadIdx.x >> 6;
    int lane = threadIdx.x & 63;
    int n = blockIdx.x * 4 + wave;
    if (n >= N_NODES) return;       // no barriers below: wave-local only
    const u32* HB32 = (const u32*)HBin;
    int nn = OWN_MAP ? own_map[n] : n;
    u32 own = HB32[(size_t)nn * 64 + lane];
    int beg = rp[n], end = rp[n + 1];
    float den0 = 0.f, den1 = 0.f, num0 = 0.f, num1 = 0.f;
    for (int c = beg; c < end; c += 16) {
        int cnt = end - c; if (cnt > 16) cnt = 16;
        int e = c + (lane & 15); if (e > end - 1) e = end - 1;
        int ei = eidx[e];                       // lanes 0..15 hold the ids
        int nI = (cnt + 3) >> 2;
        #pragma unroll
        for (int i = 0; i < 4; ++i) {
            if (i < nI) {
                int s = __shfl(ei, i * 4 + (lane >> 4), 64);
                __builtin_amdgcn_global_load_lds(
                    GPTR((const char*)HBin + (size_t)s * 256 + (lane & 15) * 16),
                    LPTR(&RS[wave][i * 4][0]), 16, 0, 0);
            }
        }
        asm volatile("s_waitcnt vmcnt(0)" ::: "memory");
        __builtin_amdgcn_sched_barrier(0);
        #pragma unroll
        for (int t = 0; t < 16; ++t) {
            if (t >= cnt) break;                // cnt is wave-uniform
            u32 h = RS[wave][t][lane];
            float m0 = fmaxf(bf2f((u16)(h & 0xffff)), 0.f) + 1e-7f;
            float m1 = fmaxf(bf2f((u16)(h >> 16)),    0.f) + 1e-7f;
            float e0 = __expf(m0), e1 = __expf(m1);
            den0 += e0; num0 += m0 * e0;
            den1 += e1; num1 += m1 * e1;
        }
        asm volatile("s_waitcnt lgkmcnt(0)" ::: "memory");  // reads done before
        __builtin_amdgcn_sched_barrier(0);                  // next DMA overwrite
    }
    float a0 = num0 / (den0 + 1e-16f) + bf2f((u16)(own & 0xffff));
    float a1 = num1 / (den1 + 1e-16f) + bf2f((u16)(own >> 16));
    ((u32*)Amsg)[(size_t)n * 64 + lane] = (u32)f2bf(a0) | ((u32)f2bf(a1) << 16);
}

// ---------------- Conv GEMM (v7, reverted): 64 rows/block ---------------
// R11's 128-row variant (64KB LDS, 2 blk/CU) regressed to 68us/layer:
// in this latency-bound regime occupancy beats traffic. v7 = 48KB, 3/CU.
template<bool RES, bool OWN_MAP, bool WRITE_LN>
__global__ __launch_bounds__(256) void conv_gemm_kernel(
    const u16* __restrict__ Amsg, const int* __restrict__ own_map,
    const u16* __restrict__ Bp, int Bpbase,
    const void* __restrict__ bias, int biasoff,
    const __half* __restrict__ Resid,
    const void* __restrict__ lng, const void* __restrict__ lnb, int lnoff,
    const int* __restrict__ dt,
    __half* __restrict__ OutH, u16* __restrict__ HBout)
{
    const bool f32 = (dt[1] > 16);
    __shared__ u16 Bsh[16384];      // 32KB
    __shared__ u16 Ash[8192];       // 16KB: 64 rows x 256B (swizzled)
    const int tid  = threadIdx.x;
    const int w    = tid >> 6;
    const int lane = tid & 63;
    const int quad = lane >> 4;
    const int cl   = lane & 15;
    const int m0   = blockIdx.x * 64;

    {
        const char* Bp2 = (const char*)(Bp + Bpbase);
        #pragma unroll
        for (int i = 0; i < 8; ++i)
            __builtin_amdgcn_global_load_lds(
                GPTR(Bp2 + i * 4096 + w * 1024 + lane * 16),
                LPTR((char*)Bsh + i * 4096 + w * 1024), 16, 0, 0);
        const char* Ab = (const char*)Amsg + (size_t)m0 * 256;
        #pragma unroll
        for (int i = 0; i < 4; ++i) {
            int row_local = i * 16 + w * 4 + (lane >> 4);
            int off = ((lane & 15) * 16) ^ ((row_local & 7) << 4);
            __builtin_amdgcn_global_load_lds(
                GPTR(Ab + (size_t)row_local * 256 + off),
                LPTR((char*)Ash + i * 4096 + w * 1024), 16, 0, 0);
        }
    }

    __syncthreads();    // vmcnt(0) drain + barrier (compiler-emitted)

    const int row_local = w * 16 + cl;
    const char* ar = (const char*)Ash + row_local * 256;
    const int akey = (row_local & 7) << 4;
    bf16x8 afr[4];
    #pragma unroll
    for (int kidx = 0; kidx < 4; ++kidx)
        afr[kidx] = *(const bf16x8*)(ar + ((kidx * 64 + quad * 16) ^ akey));

    f32x4 acc[8];
    #pragma unroll
    for (int ct = 0; ct < 8; ++ct) acc[ct] = (f32x4){0.f, 0.f, 0.f, 0.f};
    #pragma unroll
    for (int kidx = 0; kidx < 4; ++kidx) {
        const u16* bb = Bsh + ((size_t)(kidx * 8) * 64 + lane) * 8;
        #pragma unroll
        for (int ct = 0; ct < 8; ++ct) {
            bf16x8 b = *(const bf16x8*)(bb + (size_t)ct * 512);
            acc[ct] = __builtin_amdgcn_mfma_f32_16x16x32_bf16(afr[kidx], b, acc[ct], 0, 0, 0);
        }
    }

    #pragma unroll
    for (int reg = 0; reg < 4; ++reg) {
        int n = m0 + w * 16 + quad * 4 + reg;
        if (n >= N_NODES) continue;
        size_t rrow = 0;
        if (RES) rrow = (size_t)(OWN_MAP ? own_map[n] : n) * HDIM;
        float v[8];
        float s1 = 0.f, s2 = 0.f;
        #pragma unroll
        for (int ct = 0; ct < 8; ++ct) {
            int col = ct * 16 + cl;
            float x = acc[ct][reg] + loadF(bias, biasoff + col, f32);
            if (RES) x += __half2float(Resid[rrow + col]);
            v[ct] = x;
            OutH[(size_t)n * HDIM + col] = __float2half(x);
            s1 += x; s2 += x * x;
        }
        if (WRITE_LN) {
            #pragma unroll
            for (int o = 1; o < 16; o <<= 1) {
                s1 += __shfl_xor(s1, o, 64);
                s2 += __shfl_xor(s2, o, 64);
            }
            float mu = s1 * (1.0f / 128.0f);
            float var = s2 * (1.0f / 128.0f) - mu * mu;
            float rs = rsqrtf(fmaxf(var, 0.f) + 1e-5f);
            #pragma unroll
            for (int ct = 0; ct < 8; ++ct) {
                int col = ct * 16 + cl;
                float y = fmaxf((v[ct] - mu) * rs * loadF(lng, lnoff + col, f32)
                                + loadF(lnb, lnoff + col, f32), 0.f);
                HBout[(size_t)n * HDIM + col] = f2bf(y);
            }
        }
    }
}

// ---------------- Final head v3: 16 seeds/block (pred_w restage /4) -----
__global__ __launch_bounds__(256) void final_head_kernel(
    const __half* __restrict__ Hsrc, const int* __restrict__ map1,
    const int* __restrict__ fmap,
    const void* __restrict__ g, const void* __restrict__ b, int goff,
    const void* __restrict__ pw, const void* __restrict__ pb,
    const int* __restrict__ dt, void* __restrict__ out)
{
    const bool f32 = (dt[1] > 16);
    __shared__ float pwl[HDIM * 48];    // 24KB, stride-48-padded [k][cls]
    __shared__ float pbl[64];
    __shared__ float sh[4][4][HDIM];    // 8KB: [wave][seed][feat]
    const int tid = threadIdx.x, wave = tid >> 6, lane = tid & 63;

    for (int i = tid; i < HDIM * NCLS; i += 256)
        pwl[(i / NCLS) * 48 + (i % NCLS)] = loadF(pw, i, f32);
    if (tid < NCLS) pbl[tid] = loadF(pb, tid, f32);
    __syncthreads();

    #pragma unroll
    for (int js = 0; js < 4; ++js) {
        int i = blockIdx.x * 16 + wave * 4 + js;    // NOUT_D = 625*16
        int jj = map1[fmap[i]];
        __half2 hv = *((const __half2*)(Hsrc + (size_t)jj * HDIM) + lane);
        float2 v = __half22float2(hv);
        float mu = wave_sum(v.x + v.y) * (1.0f / 128.0f);
        float d0 = v.x - mu, d1 = v.y - mu;
        float var = wave_sum(d0 * d0 + d1 * d1) * (1.0f / 128.0f);
        float rs = rsqrtf(var + 1e-5f);
        int f0 = lane * 2;
        sh[wave][js][f0]     = fmaxf(d0 * rs * loadF(g, goff + f0, f32)     + loadF(b, goff + f0, f32),     0.0f);
        sh[wave][js][f0 + 1] = fmaxf(d1 * rs * loadF(g, goff + f0 + 1, f32) + loadF(b, goff + f0 + 1, f32), 0.0f);
        // wave-local LDS write->read; compiler inserts lgkmcnt, no barrier
        float acc = -1e30f;
        if (lane < NCLS) {
            acc = pbl[lane];
            #pragma unroll 8
            for (int k = 0; k < HDIM; ++k)
                acc = fmaf(sh[wave][js][k], pwl[k * 48 + lane], acc);
        }
        float mx = wave_max(acc);
        float ex = (lane < NCLS) ? __expf(acc - mx) : 0.0f;
        float sum = wave_sum(ex);
        if (lane < NCLS) {
            float r = acc - mx - logf(sum);
            if (f32) ((float*)out)[(size_t)i * NCLS + lane] = r;
            else     ((u16*)out)[(size_t)i * NCLS + lane] = f2bf(r);
        }
    }
}

extern "C" void kernel_launch(void* const* d_in, const int* in_sizes, int n_in,
                              void* d_out, int out_size, void* d_ws, size_t ws_size,
                              hipStream_t stream) {
    const void* x       = d_in[0];
    const int* src      = (const int*)d_in[1];
    const int* dst      = (const int*)d_in[2];
    const int* node_map = (const int*)d_in[3];
    const int* fmap     = (const int*)d_in[4];
    const void* enc_w   = d_in[5];
    const void* enc_b   = d_in[6];
    const void* gcn_w   = d_in[7];
    const void* gcn_b   = d_in[8];
    const void* ln_g    = d_in[9];
    const void* ln_b    = d_in[10];
    const void* pred_w  = d_in[11];
    const void* pred_b  = d_in[12];

    char* ws = (char*)d_ws;
    const size_t szH = (size_t)N_NODES * HDIM * sizeof(u16);     // 25.6 MB
    __half* Pa  = (__half*)ws;  ws += szH;   // h1, then h3 (fp16)
    __half* Pb  = (__half*)ws;  ws += szH;   // h2 (fp16)
    u16*   HBa  = (u16*)ws;     ws += szH;   // msg0, then msg2 (bf16)
    u16*   HBb  = (u16*)ws;     ws += szH;   // msg1 (bf16)
    u16*   Amsg = (u16*)ws;     ws += szH;   // per-layer GEMM A matrix (bf16)
    int*   FLAG = (int*)ws;     ws += 1024;
    u16*   Bp   = (u16*)ws;     ws += (size_t)(32768 + 3 * 16384) * 2 + 1024;
    int*  rp0   = (int*)ws;  ws += (size_t)(N_NODES + 2) * 4;
    int*  rp1   = (int*)ws;  ws += (size_t)(N_NODES + 2) * 4;
    int*  ei0   = (int*)ws;  ws += (size_t)N_EDGES * 4;
    int*  ei1   = (int*)ws;  ws += (size_t)N_EDGES * 4;
    u32*  tmp   = (u32*)ws;  ws += (size_t)2 * N_EDGES * 4;      // packed
    int*  csum  = (int*)ws;  ws += 2048;
    int*  coff  = (int*)ws;  ws += 2048;
    int*  bcur  = (int*)ws;  ws += (size_t)2 * NCHUNK * 16 * 4 + 1024;  // padded

    dim3 blk(256);
    const int g64   = (N_NODES + 63) / 64;       // 1563 (conv, 64 rows/blk)
    const int g16   = (N_NODES + 15) / 16;       // 6250 (enc, 16 rows/blk)
    const int ebgrid = (N_EDGES + EB - 1) / EB;  // 586
    const int agrid = (N_NODES + 3) / 4;
    const int pgrid = (32768 + 3 * 16384 + 255) / 256;

    hipMemsetAsync(FLAG, 0, 64, stream);
    hipMemsetAsync(csum, 0, 2048, stream);
    dtype_detect_kernel<<<256, blk, 0, stream>>>((const u16*)x, FLAG);
    pack_b_kernel<<<pgrid, blk, 0, stream>>>(enc_w, gcn_w, FLAG, Bp);

    // ---- CSR build v11: bucket-hist -> coff -> partition -> sort(+rp) ----
    histb_kernel<<<2 * ebgrid, blk, 0, stream>>>(dst, csum, ebgrid);
    coff2_kernel<<<1, blk, 0, stream>>>(csum, coff, bcur);
    bucket_part_kernel<<<2 * PNB, blk, 0, stream>>>(src, dst, node_map, bcur, tmp);
    bucket_sort_kernel<<<2 * NCHUNK, blk, 0, stream>>>(tmp, coff, csum,
                                                       rp0, rp1, ei0, ei1);

    // encoder: HBa = bf16(x @ enc_w + enc_b)   (= msg matrix for conv0)
    enc_gemm_kernel<<<g16, blk, 81920, stream>>>(x, Bp, enc_b, FLAG, HBa);

    // layer 0: Amsg = agg0(HBa)+HBa ; Pa = Amsg@w0+b0 ; HBb = relu(LN(Pa,ln0))
    agg_msg_kernel<false><<<agrid, blk, 0, stream>>>(rp0, ei0, HBa, nullptr, Amsg);
    conv_gemm_kernel<false, false, true><<<g64, blk, 0, stream>>>(
        Amsg, nullptr, Bp, 32768, gcn_b, 0, nullptr,
        ln_g, ln_b, 0, FLAG, Pa, HBb);

    // layer 1: Amsg = agg0(HBb)+HBb ; Pb = Amsg@w1+b1+Pa ; HBa = relu(LN(Pb,ln1))
    agg_msg_kernel<false><<<agrid, blk, 0, stream>>>(rp0, ei0, HBb, nullptr, Amsg);
    conv_gemm_kernel<true, false, true><<<g64, blk, 0, stream>>>(
        Amsg, nullptr, Bp, 32768 + 16384, gcn_b, 128, Pa,
        ln_g, ln_b, 128, FLAG, Pb, HBa);

    // layer 2 (permute via node_map[0]): Amsg = agg1(HBa)+HBa[map0]
    agg_msg_kernel<true><<<agrid, blk, 0, stream>>>(rp1, ei1, HBa, node_map, Amsg);
    conv_gemm_kernel<true, true, false><<<g64, blk, 0, stream>>>(
        Amsg, node_map, Bp, 32768 + 2 * 16384, gcn_b, 256, Pb,
        ln_g, ln_b, 256, FLAG, Pa, nullptr);

    // final head: Pa[node_map[1][final_map[i]]] -> LN(ln2) -> pred -> log_softmax
    final_head_kernel<<<NOUT_D / 16, blk, 0, stream>>>(
        Pa, node_map + N_NODES, fmap, ln_g, ln_b, 256, pred_w, pred_b, FLAG,
        (void*)d_out);
}

// Round 14
// 522.072 us; speedup vs baseline: 1.1145x; 1.0396x over previous
//
#include <hip/hip_runtime.h>
#include <hip/hip_bf16.h>
#include <hip/hip_fp16.h>

typedef unsigned short u16;
typedef unsigned int u32;

#define N_NODES 100000
#define N_EDGES 600000
#define FIN_D   256
#define HDIM    128
#define NCLS    47
#define NOUT_D  10000
#define NCHUNK  196          // ceil(N_NODES/512)
#define PCH     2048         // edges per partition block
#define PNB     ((N_EDGES + PCH - 1) / PCH)   // 293
#define BPAD    4096         // padded tmp entries per bucket (E[cnt]=3061, +18 sigma)
#define PADE    (NCHUNK * BPAD)               // 802816 per half

typedef short bf16x8 __attribute__((ext_vector_type(8)));
typedef float f32x4  __attribute__((ext_vector_type(4)));

#define GPTR(p) (const __attribute__((address_space(1))) u32*)(p)
#define LPTR(p) (__attribute__((address_space(3))) u32*)(p)

__device__ __forceinline__ float bf2f(u16 u) {
    union { u32 i; float f; } v; v.i = ((u32)u) << 16; return v.f;
}
__device__ __forceinline__ u16 f2bf(float f) {
    __hip_bfloat16 h = __float2bfloat16(f);
    return *reinterpret_cast<u16*>(&h);
}
__device__ __forceinline__ float loadF(const void* p, size_t i, bool f32) {
    if (f32) return ((const float*)p)[i];
    return bf2f(((const u16*)p)[i]);
}
__device__ __forceinline__ float wave_sum(float v) {
    #pragma unroll
    for (int o = 32; o > 0; o >>= 1) v += __shfl_xor(v, o, 64);
    return v;
}
__device__ __forceinline__ float wave_max(float v) {
    #pragma unroll
    for (int o = 32; o > 0; o >>= 1) v = fmaxf(v, __shfl_xor(v, o, 64));
    return v;
}
__device__ __forceinline__ int block_excl_scan_256(int v, int* wsum) {
    int lane = threadIdx.x & 63, wv = threadIdx.x >> 6;
    int inc = v;
    #pragma unroll
    for (int off = 1; off < 64; off <<= 1) {
        int u = __shfl_up(inc, off, 64);
        if (lane >= off) inc += u;
    }
    if (lane == 63) wsum[wv] = inc;
    __syncthreads();
    if (threadIdx.x == 0) {
        int a = 0;
        #pragma unroll
        for (int w = 0; w < 4; ++w) { int t = wsum[w]; wsum[w] = a; a += t; }
    }
    __syncthreads();
    return inc - v + wsum[wv];
}

// ---------------- dtype detector + bcur init ----------------------------
// v13: block 0 also initializes the 392 padded bucket cursors (replaces
// the histb pass entirely -- buckets get fixed 4096-entry tmp regions).
__global__ __launch_bounds__(256) void dtype_detect_kernel(
    const u16* __restrict__ x, int* __restrict__ flag, int* __restrict__ bcur)
{
    if (blockIdx.x == 0 && threadIdx.x < NCHUNK) {
        bcur[threadIdx.x * 16] = threadIdx.x * BPAD;
        bcur[(NCHUNK + threadIdx.x) * 16] = threadIdx.x * BPAD;
    }
    int i = blockIdx.x * 256 + threadIdx.x;     // exactly 65536 threads
    u32 e = (x[i] >> 7) & 0xFF;
    unsigned long long b = __ballot(e >= 200);
    if ((threadIdx.x & 63) == 0) {
        int c = __popcll(b);
        if (c) atomicAdd(&flag[1], c);
    }
}

// Pass 1: block-local radix partition into PADDED per-bucket regions.
// tmp packed u32: (src<<9)|(dst&511).
__global__ __launch_bounds__(256) void bucket_part_kernel(
    const int* __restrict__ src, const int* __restrict__ dst,
    const int* __restrict__ comp1,
    int* __restrict__ bcur, u32* __restrict__ tmp)
{
    __shared__ int hist[NCHUNK];
    __shared__ int base[NCHUNK];
    int half = (blockIdx.x >= PNB) ? 1 : 0;
    int b = blockIdx.x - half * PNB;
    int e0 = b * PCH;
    for (int i = threadIdx.x; i < NCHUNK; i += 256) hist[i] = 0;
    __syncthreads();

    int2 loc[8];
    #pragma unroll
    for (int t = 0; t < 8; ++t) {
        int e = e0 + t * 256 + threadIdx.x;
        loc[t].y = -1;
        if (e < N_EDGES) {
            int ge = half * N_EDGES + e;
            int d = dst[ge];
            int s = src[ge];
            if (half) s = comp1[s];
            loc[t] = make_int2(s, d);
            atomicAdd(&hist[d >> 9], 1);
        }
    }
    __syncthreads();
    for (int i = threadIdx.x; i < NCHUNK; i += 256) {
        int h = hist[i];
        base[i] = (h > 0) ? atomicAdd(&bcur[(half * NCHUNK + i) * 16], h) : 0;
        hist[i] = 0;      // reuse as block-local cursor
    }
    __syncthreads();
    #pragma unroll
    for (int t = 0; t < 8; ++t) {
        if (loc[t].y >= 0) {
            int bk = loc[t].y >> 9;
            int pos = base[bk] + atomicAdd(&hist[bk], 1);
            tmp[(size_t)half * PADE + pos] = ((u32)loc[t].x << 9) | ((u32)loc[t].y & 511);
        }
    }
}

// coff2 (v13: runs AFTER part): derive counts from final cursor values,
// exclusive-scan to compact offsets; writes coff + csum.
__global__ __launch_bounds__(256) void coff2_kernel(
    const int* __restrict__ bcur, int* __restrict__ coff,
    int* __restrict__ csum)
{
    __shared__ int wsum[4];
    int t = threadIdx.x;
    for (int h = 0; h < 2; ++h) {
        int v = 0;
        if (t < NCHUNK) v = bcur[(h * NCHUNK + t) * 16] - t * BPAD;
        int excl = block_excl_scan_256(v, wsum);
        if (t < NCHUNK) {
            coff[h * NCHUNK + t] = excl;
            csum[h * NCHUNK + t] = v;
        }
        __syncthreads();
    }
}

// Pass 2: one block per bucket; local degree histogram -> rp, rank+scatter.
// Reads from the bucket's padded tmp region; writes compact rp/ei.
__global__ __launch_bounds__(256) void bucket_sort_kernel(
    const u32* __restrict__ tmp,
    const int* __restrict__ coff, const int* __restrict__ csum,
    int* __restrict__ rp0, int* __restrict__ rp1,
    int* __restrict__ ei0, int* __restrict__ ei1)
{
    __shared__ int cur[512];
    __shared__ int wsum[4];
    int half = (blockIdx.x >= NCHUNK) ? 1 : 0;
    int b = blockIdx.x - half * NCHUNK;
    int* rp = half ? rp1 : rp0;
    int* ei = half ? ei1 : ei0;
    int n0 = b * 512;
    int cbeg = coff[half * NCHUNK + b];
    int cnt  = csum[half * NCHUNK + b];
    size_t tbeg = (size_t)half * PADE + (size_t)b * BPAD;
    const int t = threadIdx.x;

    // pass 1: local degree histogram (LDS atomics)
    cur[t] = 0; cur[t + 256] = 0;
    __syncthreads();
    for (int i = t; i < cnt; i += 256)
        atomicAdd(&cur[tmp[tbeg + i] & 511], 1);
    __syncthreads();

    // 512-entry exclusive scan (2 per thread); own-entry read/write only
    int d0 = cur[2 * t], d1 = cur[2 * t + 1];
    int excl = block_excl_scan_256(d0 + d1, wsum);
    int base = cbeg + excl;
    cur[2 * t] = base;
    cur[2 * t + 1] = base + d0;
    if (n0 + 2 * t <= N_NODES)     rp[n0 + 2 * t] = base;
    if (n0 + 2 * t + 1 <= N_NODES) rp[n0 + 2 * t + 1] = base + d0;
    __syncthreads();

    // pass 2: rank + scatter
    for (int i = t; i < cnt; i += 256) {
        u32 p = tmp[tbeg + i];
        int pos = atomicAdd(&cur[p & 511], 1);
        ei[pos] = (int)(p >> 9);
    }
}

// ---------------- Weight pre-pack into MFMA B-fragment order -----------
__global__ __launch_bounds__(256) void pack_b_kernel(
    const void* __restrict__ enc_w, const void* __restrict__ gcn_w,
    const int* __restrict__ dt, u16* __restrict__ Bp)
{
    const bool f32 = (dt[1] > 16);
    int o = blockIdx.x * 256 + threadIdx.x;
    if (o >= 32768 + 3 * 16384) return;
    const void* srcp; size_t soff; int m;
    if (o < 32768) { srcp = enc_w; soff = 0; m = o; }
    else {
        int l = (o - 32768) >> 14;
        srcp = gcn_w; soff = (size_t)l * 16384; m = (o - 32768) & 16383;
    }
    int j    = m & 7;
    int lane = (m >> 3) & 63;
    int ct   = (m >> 9) & 7;
    int kidx = m >> 12;
    int k = kidx * 32 + (lane >> 4) * 8 + j;
    int n = ct * 16 + (lane & 15);
    Bp[o] = f2bf(loadF(srcp, soff + (size_t)k * HDIM + n, f32));
}

// ---------------- Encoder GEMM (v6 structure; split in 2 dispatches) ----
__global__ __launch_bounds__(256, 2) void enc_gemm_kernel(
    const void* __restrict__ Araw, const u16* __restrict__ Bp,
    const void* __restrict__ bias, const int* __restrict__ dt,
    int rowbase, u16* __restrict__ OutBF)
{
    extern __shared__ char SH[];                  // 80KB: [0,64K)=B, [64K,80K)=A
    const bool f32 = (dt[1] > 16);
    const int tid  = threadIdx.x;
    const int w    = tid >> 6;                    // 0..3
    const int lane = tid & 63;
    const int quad = lane >> 4;
    const int cl   = lane & 15;
    const int m0   = rowbase + blockIdx.x * 16;

    #pragma unroll
    for (int i = 0; i < 16; ++i) {
        int off = (w * 16 + i) * 1024;
        __builtin_amdgcn_global_load_lds(
            GPTR((const char*)Bp + off + lane * 16),
            LPTR(SH + off), 16, 0, 0);
    }
    if (f32) {
        #pragma unroll
        for (int i = 0; i < 4; ++i) {
            int row = w * 4 + i;
            int src = (lane * 16) ^ ((row & 7) << 4);
            __builtin_amdgcn_global_load_lds(
                GPTR((const char*)Araw + (size_t)(m0 + row) * 1024 + src),
                LPTR(SH + 65536 + row * 1024), 16, 0, 0);
        }
    } else {
        #pragma unroll
        for (int i = 0; i < 2; ++i) {
            int r0 = (w * 2 + i) * 2;
            int row = r0 + (lane >> 5);
            int src = ((lane & 31) * 16) ^ ((row & 7) << 4);
            __builtin_amdgcn_global_load_lds(
                GPTR((const char*)Araw + (size_t)(m0 + row) * 512 + src),
                LPTR(SH + 65536 + r0 * 512), 16, 0, 0);
        }
    }

    f32x4 acc[2];
    acc[0] = (f32x4){0.f, 0.f, 0.f, 0.f};
    acc[1] = (f32x4){0.f, 0.f, 0.f, 0.f};
    const int ct0 = w * 2;
    const int swz = (cl & 7) << 4;

    __syncthreads();

    #pragma unroll
    for (int k = 0; k < 8; ++k) {
        bf16x8 av;
        if (f32) {
            const char* rb = SH + 65536 + cl * 1024;
            int lo = (k * 128 + quad * 32) ^ swz;
            float4 v0 = *(const float4*)(rb + lo);
            float4 v1 = *(const float4*)(rb + (lo ^ 16));
            union { u32 u[4]; bf16x8 v; } cv;
            cv.u[0] = (u32)f2bf(v0.x) | ((u32)f2bf(v0.y) << 16);
            cv.u[1] = (u32)f2bf(v0.z) | ((u32)f2bf(v0.w) << 16);
            cv.u[2] = (u32)f2bf(v1.x) | ((u32)f2bf(v1.y) << 16);
            cv.u[3] = (u32)f2bf(v1.z) | ((u32)f2bf(v1.w) << 16);
            av = cv.v;
        } else {
            const char* rb = SH + 65536 + cl * 512;
            av = *(const bf16x8*)(rb + ((k * 64 + quad * 16) ^ swz));
        }
        #pragma unroll
        for (int c = 0; c < 2; ++c) {
            bf16x8 b = *(const bf16x8*)(SH + k * 8192 + (ct0 + c) * 1024 + lane * 16);
            acc[c] = __builtin_amdgcn_mfma_f32_16x16x32_bf16(av, b, acc[c], 0, 0, 0);
        }
    }

    #pragma unroll
    for (int reg = 0; reg < 4; ++reg) {
        int grow = m0 + quad * 4 + reg;
        #pragma unroll
        for (int c = 0; c < 2; ++c) {
            int col = (ct0 + c) * 16 + cl;
            float v = acc[c][reg] + loadF(bias, col, f32);
            OutBF[(size_t)grow * HDIM + col] = f2bf(v);
        }
    }
}

// ---------------- Softmax aggregation -> bf16 A-matrix (v7) -------------
template<bool OWN_MAP>
__global__ __launch_bounds__(256) void agg_msg_kernel(
    const int* __restrict__ rp, const int* __restrict__ eidx,
    const u16* __restrict__ HBin, const int* __restrict__ own_map,
    u16* __restrict__ Amsg)
{
    __shared__ u32 RS[4][16][64];   // 16KB: per-wave staging of 16 rows
    int wave = threadIdx.x >> 6;
    int lane = threadIdx.x & 63;
    int n = blockIdx.x * 4 + wave;
    if (n >= N_NODES) return;       // no barriers below: wave-local only
    const u32* HB32 = (const u32*)HBin;
    int nn = OWN_MAP ? own_map[n] : n;
    u32 own = HB32[(size_t)nn * 64 + lane];
    int beg = rp[n], end = rp[n + 1];
    float den0 = 0.f, den1 = 0.f, num0 = 0.f, num1 = 0.f;
    for (int c = beg; c < end; c += 16) {
        int cnt = end - c; if (cnt > 16) cnt = 16;
        int e = c + (lane & 15); if (e > end - 1) e = end - 1;
        int ei = eidx[e];                       // lanes 0..15 hold the ids
        int nI = (cnt + 3) >> 2;
        #pragma unroll
        for (int i = 0; i < 4; ++i) {
            if (i < nI) {
                int s = __shfl(ei, i * 4 + (lane >> 4), 64);
                __builtin_amdgcn_global_load_lds(
                    GPTR((const char*)HBin + (size_t)s * 256 + (lane & 15) * 16),
                    LPTR(&RS[wave][i * 4][0]), 16, 0, 0);
            }
        }
        asm volatile("s_waitcnt vmcnt(0)" ::: "memory");
        __builtin_amdgcn_sched_barrier(0);
        #pragma unroll
        for (int t = 0; t < 16; ++t) {
            if (t >= cnt) break;                // cnt is wave-uniform
            u32 h = RS[wave][t][lane];
            float m0 = fmaxf(bf2f((u16)(h & 0xffff)), 0.f) + 1e-7f;
            float m1 = fmaxf(bf2f((u16)(h >> 16)),    0.f) + 1e-7f;
            float e0 = __expf(m0), e1 = __expf(m1);
            den0 += e0; num0 += m0 * e0;
            den1 += e1; num1 += m1 * e1;
        }
        asm volatile("s_waitcnt lgkmcnt(0)" ::: "memory");  // reads done before
        __builtin_amdgcn_sched_barrier(0);                  // next DMA overwrite
    }
    float a0 = num0 / (den0 + 1e-16f) + bf2f((u16)(own & 0xffff));
    float a1 = num1 / (den1 + 1e-16f) + bf2f((u16)(own >> 16));
    ((u32*)Amsg)[(size_t)n * 64 + lane] = (u32)f2bf(a0) | ((u32)f2bf(a1) << 16);
}

// ---------------- Conv GEMM (v7): 64 rows/block, 48KB LDS, 3 blk/CU -----
template<bool RES, bool OWN_MAP, bool WRITE_LN>
__global__ __launch_bounds__(256) void conv_gemm_kernel(
    const u16* __restrict__ Amsg, const int* __restrict__ own_map,
    const u16* __restrict__ Bp, int Bpbase,
    const void* __restrict__ bias, int biasoff,
    const __half* __restrict__ Resid,
    const void* __restrict__ lng, const void* __restrict__ lnb, int lnoff,
    const int* __restrict__ dt,
    __half* __restrict__ OutH, u16* __restrict__ HBout)
{
    const bool f32 = (dt[1] > 16);
    __shared__ u16 Bsh[16384];      // 32KB
    __shared__ u16 Ash[8192];       // 16KB: 64 rows x 256B (swizzled)
    const int tid  = threadIdx.x;
    const int w    = tid >> 6;
    const int lane = tid & 63;
    const int quad = lane >> 4;
    const int cl   = lane & 15;
    const int m0   = blockIdx.x * 64;

    {
        const char* Bp2 = (const char*)(Bp + Bpbase);
        #pragma unroll
        for (int i = 0; i < 8; ++i)
            __builtin_amdgcn_global_load_lds(
                GPTR(Bp2 + i * 4096 + w * 1024 + lane * 16),
                LPTR((char*)Bsh + i * 4096 + w * 1024), 16, 0, 0);
        const char* Ab = (const char*)Amsg + (size_t)m0 * 256;
        #pragma unroll
        for (int i = 0; i < 4; ++i) {
            int row_local = i * 16 + w * 4 + (lane >> 4);
            int off = ((lane & 15) * 16) ^ ((row_local & 7) << 4);
            __builtin_amdgcn_global_load_lds(
                GPTR(Ab + (size_t)row_local * 256 + off),
                LPTR((char*)Ash + i * 4096 + w * 1024), 16, 0, 0);
        }
    }

    __syncthreads();    // vmcnt(0) drain + barrier (compiler-emitted)

    const int row_local = w * 16 + cl;
    const char* ar = (const char*)Ash + row_local * 256;
    const int akey = (row_local & 7) << 4;
    bf16x8 afr[4];
    #pragma unroll
    for (int kidx = 0; kidx < 4; ++kidx)
        afr[kidx] = *(const bf16x8*)(ar + ((kidx * 64 + quad * 16) ^ akey));

    f32x4 acc[8];
    #pragma unroll
    for (int ct = 0; ct < 8; ++ct) acc[ct] = (f32x4){0.f, 0.f, 0.f, 0.f};
    #pragma unroll
    for (int kidx = 0; kidx < 4; ++kidx) {
        const u16* bb = Bsh + ((size_t)(kidx * 8) * 64 + lane) * 8;
        #pragma unroll
        for (int ct = 0; ct < 8; ++ct) {
            bf16x8 b = *(const bf16x8*)(bb + (size_t)ct * 512);
            acc[ct] = __builtin_amdgcn_mfma_f32_16x16x32_bf16(afr[kidx], b, acc[ct], 0, 0, 0);
        }
    }

    #pragma unroll
    for (int reg = 0; reg < 4; ++reg) {
        int n = m0 + w * 16 + quad * 4 + reg;
        if (n >= N_NODES) continue;
        size_t rrow = 0;
        if (RES) rrow = (size_t)(OWN_MAP ? own_map[n] : n) * HDIM;
        float v[8];
        float s1 = 0.f, s2 = 0.f;
        #pragma unroll
        for (int ct = 0; ct < 8; ++ct) {
            int col = ct * 16 + cl;
            float x = acc[ct][reg] + loadF(bias, biasoff + col, f32);
            if (RES) x += __half2float(Resid[rrow + col]);
            v[ct] = x;
            OutH[(size_t)n * HDIM + col] = __float2half(x);
            s1 += x; s2 += x * x;
        }
        if (WRITE_LN) {
            #pragma unroll
            for (int o = 1; o < 16; o <<= 1) {
                s1 += __shfl_xor(s1, o, 64);
                s2 += __shfl_xor(s2, o, 64);
            }
            float mu = s1 * (1.0f / 128.0f);
            float var = s2 * (1.0f / 128.0f) - mu * mu;
            float rs = rsqrtf(fmaxf(var, 0.f) + 1e-5f);
            #pragma unroll
            for (int ct = 0; ct < 8; ++ct) {
                int col = ct * 16 + cl;
                float y = fmaxf((v[ct] - mu) * rs * loadF(lng, lnoff + col, f32)
                                + loadF(lnb, lnoff + col, f32), 0.f);
                HBout[(size_t)n * HDIM + col] = f2bf(y);
            }
        }
    }
}

// ---------------- Final head v3: 16 seeds/block (pred_w restage /4) -----
__global__ __launch_bounds__(256) void final_head_kernel(
    const __half* __restrict__ Hsrc, const int* __restrict__ map1,
    const int* __restrict__ fmap,
    const void* __restrict__ g, const void* __restrict__ b, int goff,
    const void* __restrict__ pw, const void* __restrict__ pb,
    const int* __restrict__ dt, void* __restrict__ out)
{
    const bool f32 = (dt[1] > 16);
    __shared__ float pwl[HDIM * 48];    // 24KB, stride-48-padded [k][cls]
    __shared__ float pbl[64];
    __shared__ float sh[4][4][HDIM];    // 8KB: [wave][seed][feat]
    const int tid = threadIdx.x, wave = tid >> 6, lane = tid & 63;

    for (int i = tid; i < HDIM * NCLS; i += 256)
        pwl[(i / NCLS) * 48 + (i % NCLS)] = loadF(pw, i, f32);
    if (tid < NCLS) pbl[tid] = loadF(pb, tid, f32);
    __syncthreads();

    #pragma unroll
    for (int js = 0; js < 4; ++js) {
        int i = blockIdx.x * 16 + wave * 4 + js;    // NOUT_D = 625*16
        int jj = map1[fmap[i]];
        __half2 hv = *((const __half2*)(Hsrc + (size_t)jj * HDIM) + lane);
        float2 v = __half22float2(hv);
        float mu = wave_sum(v.x + v.y) * (1.0f / 128.0f);
        float d0 = v.x - mu, d1 = v.y - mu;
        float var = wave_sum(d0 * d0 + d1 * d1) * (1.0f / 128.0f);
        float rs = rsqrtf(var + 1e-5f);
        int f0 = lane * 2;
        sh[wave][js][f0]     = fmaxf(d0 * rs * loadF(g, goff + f0, f32)     + loadF(b, goff + f0, f32),     0.0f);
        sh[wave][js][f0 + 1] = fmaxf(d1 * rs * loadF(g, goff + f0 + 1, f32) + loadF(b, goff + f0 + 1, f32), 0.0f);
        // wave-local LDS write->read; compiler inserts lgkmcnt, no barrier
        float acc = -1e30f;
        if (lane < NCLS) {
            acc = pbl[lane];
            #pragma unroll 8
            for (int k = 0; k < HDIM; ++k)
                acc = fmaf(sh[wave][js][k], pwl[k * 48 + lane], acc);
        }
        float mx = wave_max(acc);
        float ex = (lane < NCLS) ? __expf(acc - mx) : 0.0f;
        float sum = wave_sum(ex);
        if (lane < NCLS) {
            float r = acc - mx - logf(sum);
            if (f32) ((float*)out)[(size_t)i * NCLS + lane] = r;
            else     ((u16*)out)[(size_t)i * NCLS + lane] = f2bf(r);
        }
    }
}

extern "C" void kernel_launch(void* const* d_in, const int* in_sizes, int n_in,
                              void* d_out, int out_size, void* d_ws, size_t ws_size,
                              hipStream_t stream) {
    const void* x       = d_in[0];
    const int* src      = (const int*)d_in[1];
    const int* dst      = (const int*)d_in[2];
    const int* node_map = (const int*)d_in[3];
    const int* fmap     = (const int*)d_in[4];
    const void* enc_w   = d_in[5];
    const void* enc_b   = d_in[6];
    const void* gcn_w   = d_in[7];
    const void* gcn_b   = d_in[8];
    const void* ln_g    = d_in[9];
    const void* ln_b    = d_in[10];
    const void* pred_w  = d_in[11];
    const void* pred_b  = d_in[12];

    char* ws = (char*)d_ws;
    const size_t szH = (size_t)N_NODES * HDIM * sizeof(u16);     // 25.6 MB
    __half* Pa  = (__half*)ws;  ws += szH;   // h1, then h3 (fp16)
    __half* Pb  = (__half*)ws;  ws += szH;   // h2 (fp16)
    u16*   HBa  = (u16*)ws;     ws += szH;   // msg0, then msg2 (bf16)
    u16*   HBb  = (u16*)ws;     ws += szH;   // msg1 (bf16)
    u16*   Amsg = (u16*)ws;     ws += szH;   // per-layer GEMM A matrix (bf16)
    int*   FLAG = (int*)ws;     ws += 1024;
    u16*   Bp   = (u16*)ws;     ws += (size_t)(32768 + 3 * 16384) * 2 + 1024;
    int*  rp0   = (int*)ws;  ws += (size_t)(N_NODES + 2) * 4;
    int*  rp1   = (int*)ws;  ws += (size_t)(N_NODES + 2) * 4;
    int*  ei0   = (int*)ws;  ws += (size_t)N_EDGES * 4;
    int*  ei1   = (int*)ws;  ws += (size_t)N_EDGES * 4;
    u32*  tmp   = (u32*)ws;  ws += (size_t)2 * PADE * 4;         // padded regions
    int*  csum  = (int*)ws;  ws += 2048;
    int*  coff  = (int*)ws;  ws += 2048;
    int*  bcur  = (int*)ws;  ws += (size_t)2 * NCHUNK * 16 * 4 + 1024;  // padded

    dim3 blk(256);
    const int g64   = (N_NODES + 63) / 64;       // 1563 (conv, 64 rows/blk)
    const int gHALF = 3125;                      // enc: 50000 rows per half
    const int agrid = (N_NODES + 3) / 4;
    const int pgrid = (32768 + 3 * 16384 + 255) / 256;

    hipMemsetAsync(FLAG, 0, 64, stream);
    dtype_detect_kernel<<<256, blk, 0, stream>>>((const u16*)x, FLAG, bcur);
    pack_b_kernel<<<pgrid, blk, 0, stream>>>(enc_w, gcn_w, FLAG, Bp);

    // ---- CSR build v13: part(padded regions) -> coff(scan) -> sort(+rp) ----
    bucket_part_kernel<<<2 * PNB, blk, 0, stream>>>(src, dst, node_map, bcur, tmp);
    coff2_kernel<<<1, blk, 0, stream>>>(bcur, coff, csum);
    bucket_sort_kernel<<<2 * NCHUNK, blk, 0, stream>>>(tmp, coff, csum,
                                                       rp0, rp1, ei0, ei1);

    // encoder: HBa = bf16(x @ enc_w + enc_b)  (split for top-5 visibility)
    enc_gemm_kernel<<<gHALF, blk, 81920, stream>>>(x, Bp, enc_b, FLAG, 0, HBa);
    enc_gemm_kernel<<<gHALF, blk, 81920, stream>>>(x, Bp, enc_b, FLAG, 50000, HBa);

    // layer 0: Amsg = agg0(HBa)+HBa ; Pa = Amsg@w0+b0 ; HBb = relu(LN(Pa,ln0))
    agg_msg_kernel<false><<<agrid, blk, 0, stream>>>(rp0, ei0, HBa, nullptr, Amsg);
    conv_gemm_kernel<false, false, true><<<g64, blk, 0, stream>>>(
        Amsg, nullptr, Bp, 32768, gcn_b, 0, nullptr,
        ln_g, ln_b, 0, FLAG, Pa, HBb);

    // layer 1: Amsg = agg0(HBb)+HBb ; Pb = Amsg@w1+b1+Pa ; HBa = relu(LN(Pb,ln1))
    agg_msg_kernel<false><<<agrid, blk, 0, stream>>>(rp0, ei0, HBb, nullptr, Amsg);
    conv_gemm_kernel<true, false, true><<<g64, blk, 0, stream>>>(
        Amsg, nullptr, Bp, 32768 + 16384, gcn_b, 128, Pa,
        ln_g, ln_b, 128, FLAG, Pb, HBa);

    // layer 2 (permute via node_map[0]): Amsg = agg1(HBa)+HBa[map0]
    agg_msg_kernel<true><<<agrid, blk, 0, stream>>>(rp1, ei1, HBa, node_map, Amsg);
    conv_gemm_kernel<true, true, false><<<g64, blk, 0, stream>>>(
        Amsg, node_map, Bp, 32768 + 2 * 16384, gcn_b, 256, Pb,
        ln_g, ln_b, 256, FLAG, Pa, nullptr);

    // final head: Pa[node_map[1][final_map[i]]] -> LN(ln2) -> pred -> log_softmax
    final_head_kernel<<<NOUT_D / 16, blk, 0, stream>>>(
        Pa, node_map + N_NODES, fmap, ln_g, ln_b, 256, pred_w, pred_b, FLAG,
        (void*)d_out);
}